// Round 1
// baseline (105.007 us; speedup 1.0000x reference)
//
#include <hip/hip_runtime.h>

// Problem constants
#define D_B 8
#define N_T 2048
#define NN  64
#define N_H 8
#define N_C 32   // u-chunks of 64
#define NP  72   // padded LDS row stride (bf16): 144 B rows, 16B-aligned, 2-way alias (free)

typedef __bf16 bf16;
typedef bf16 bf16x8 __attribute__((ext_vector_type(8)));
typedef bf16 bf16x4 __attribute__((ext_vector_type(4)));
typedef float f32x4 __attribute__((ext_vector_type(4)));

static __device__ __forceinline__ f32x4 mfma16(bf16x8 a, bf16x8 b, f32x4 c) {
    // a_frag[j] = A[lane&15][(lane>>4)*8+j]; b_frag[j] = B[(lane>>4)*8+j][lane&15]
    // d[r] = D[(lane>>4)*4+r][lane&15]
    return __builtin_amdgcn_mfma_f32_16x16x32_bf16(a, b, c, 0, 0, 0);
}

static __device__ __forceinline__ bf16x8 ldcvt8(const float* p) {
    const f32x4 v0 = *(const f32x4*)p;
    const f32x4 v1 = *(const f32x4*)(p + 4);
    bf16x8 r;
#pragma unroll
    for (int k = 0; k < 4; k++) { r[k] = (bf16)v0[k]; r[4 + k] = (bf16)v1[k]; }
    return r;
}

// ---------------------------------------------------------------------------
// K1 (unchanged, R8/R9-proven): block (b, c, qt) handles heads {2qt, 2qt+1}:
//   Qrd[b,c,h][u][i'] (direct store), Erd[b,c,h][i][u] (LDS-transposed flush),
//   dGq[b,c,qt][i][i'] (pre-transposed bf16), Rbf (qt==0).
// R A-frags direct from global fp32. 36.9 KB LDS -> 4 blocks/CU.
// Grid (D_B, N_C, 4): linear%8 = b (XCD-local).
// ---------------------------------------------------------------------------
__global__ __launch_bounds__(256, 4) void k_dg(
    const float* __restrict__ rp, const float* __restrict__ Qm,
    const float* __restrict__ Em,
    bf16* __restrict__ dGq, bf16* __restrict__ Rbf,
    bf16* __restrict__ Qrd, bf16* __restrict__ Erd)
{
    __shared__ bf16 Ql[64 * NP];   // Q_h [i'][j]
    __shared__ bf16 El[64 * NP];   // E_h [i][j]
    __shared__ bf16 QT[64 * NP];   // Qr tile [i'][u]; dG [i][i'] staging at tail
    __shared__ bf16 ET[64 * NP];   // Er tile [i][u]
    const int b = blockIdx.x, c = blockIdx.y, qt = blockIdx.z;
    const int tid = threadIdx.x;
    const int w = tid >> 6, l = tid & 63, q = l >> 4, l16 = l & 15;
    const int row = tid >> 2, col = (tid & 3) * 16;

    // R A-frags straight from global fp32 (rows u = c*64 + w*16 + l16)
    const float* rrow = rp + ((size_t)b * N_T + c * 64 + w * 16 + l16) * NN;
    const bf16x8 a0 = ldcvt8(rrow + q * 8);
    const bf16x8 a1 = ldcvt8(rrow + 32 + q * 8);

    if (qt == 0) {
        const float* src = rp + ((size_t)b * N_T + c * 64 + row) * NN + col;
        bf16* d = Rbf + ((size_t)b * N_T + c * 64 + row) * NN + col;
        *(bf16x8*)d       = ldcvt8(src);
        *(bf16x8*)(d + 8) = ldcvt8(src + 8);
    }

    f32x4 dacc[4];
#pragma unroll
    for (int ns = 0; ns < 4; ns++) { f32x4 z = {0.f, 0.f, 0.f, 0.f}; dacc[ns] = z; }

    for (int hh = 0; hh < 2; hh++) {
        const int h = qt * 2 + hh;
        {
            const float* qs = Qm + (size_t)h * 4096 + row * 64 + col;
            const float* es = Em + (size_t)h * 4096 + row * 64 + col;
            *(bf16x8*)&Ql[row * NP + col]     = ldcvt8(qs);
            *(bf16x8*)&Ql[row * NP + col + 8] = ldcvt8(qs + 8);
            *(bf16x8*)&El[row * NP + col]     = ldcvt8(es);
            *(bf16x8*)&El[row * NP + col + 8] = ldcvt8(es + 8);
        }
        __syncthreads();
        const size_t tb = (((size_t)(b * N_C + c)) * N_H + h) * 4096;
#pragma unroll
        for (int ns = 0; ns < 4; ns++) {
            bf16x8 b0 = *(const bf16x8*)&Ql[(ns * 16 + l16) * NP + q * 8];
            bf16x8 b1 = *(const bf16x8*)&Ql[(ns * 16 + l16) * NP + 32 + q * 8];
            f32x4 z = {0.f, 0.f, 0.f, 0.f};
            f32x4 s = mfma16(a0, b0, z);
            s = mfma16(a1, b1, s);
            bf16x4 p;
#pragma unroll
            for (int r = 0; r < 4; r++) p[r] = (bf16)s[r];
#pragma unroll
            for (int r = 0; r < 4; r++)
                Qrd[tb + (w * 16 + q * 4 + r) * 64 + ns * 16 + l16] = p[r];
            *(bf16x4*)&QT[(ns * 16 + l16) * NP + w * 16 + q * 4] = p;  // [i'][u]
            b0 = *(const bf16x8*)&El[(ns * 16 + l16) * NP + q * 8];
            b1 = *(const bf16x8*)&El[(ns * 16 + l16) * NP + 32 + q * 8];
            f32x4 s2 = mfma16(a0, b0, z);
            s2 = mfma16(a1, b1, s2);
#pragma unroll
            for (int r = 0; r < 4; r++) p[r] = (bf16)s2[r];
            *(bf16x4*)&ET[(ns * 16 + l16) * NP + w * 16 + q * 4] = p;  // [i][u]
        }
        __syncthreads();
        {
            const bf16x8 qa0 = *(const bf16x8*)&QT[(w * 16 + l16) * NP + q * 8];
            const bf16x8 qa1 = *(const bf16x8*)&QT[(w * 16 + l16) * NP + 32 + q * 8];
#pragma unroll
            for (int ns = 0; ns < 4; ns++) {
                const bf16x8 e0 = *(const bf16x8*)&ET[(ns * 16 + l16) * NP + q * 8];
                const bf16x8 e1 = *(const bf16x8*)&ET[(ns * 16 + l16) * NP + 32 + q * 8];
                dacc[ns] = mfma16(qa0, e0, dacc[ns]);
                dacc[ns] = mfma16(qa1, e1, dacc[ns]);
            }
        }
        {
            const bf16x8 v0 = *(const bf16x8*)&ET[row * NP + col];
            const bf16x8 v1 = *(const bf16x8*)&ET[row * NP + col + 8];
            bf16* d = Erd + tb + row * 64 + col;
            *(bf16x8*)d = v0;
            *(bf16x8*)(d + 8) = v1;
        }
        __syncthreads();
    }
#pragma unroll
    for (int ns = 0; ns < 4; ns++) {
        bf16x4 p;
#pragma unroll
        for (int r = 0; r < 4; r++) p[r] = (bf16)dacc[ns][r];
        *(bf16x4*)&QT[(ns * 16 + l16) * NP + w * 16 + q * 4] = p;
    }
    __syncthreads();
    {
        bf16* dst = dGq + (((size_t)(b * N_C + c)) * 4 + qt) * 4096 + row * 64 + col;
        *(bf16x8*)dst       = *(const bf16x8*)&QT[row * NP + col];
        *(bf16x8*)(dst + 8) = *(const bf16x8*)&QT[row * NP + col + 8];
    }
}

// ---------------------------------------------------------------------------
// K2: fold the 4 head-quarters: dG8[b,c] = sum_qt dGq[b,c,qt]. (unchanged)
// ---------------------------------------------------------------------------
__global__ __launch_bounds__(256, 4) void k_fold(const bf16* __restrict__ dGq,
                                                 bf16* __restrict__ dG8)
{
    const int b = blockIdx.x, c = blockIdx.y;
    const size_t base = ((size_t)(b * N_C + c)) * 4 * 4096 + threadIdx.x * 16;
    float s[16];
#pragma unroll
    for (int k = 0; k < 16; k++) s[k] = 0.f;
#pragma unroll
    for (int qt = 0; qt < 4; qt++) {
        const bf16x8 v0 = *(const bf16x8*)(dGq + base + (size_t)qt * 4096);
        const bf16x8 v1 = *(const bf16x8*)(dGq + base + (size_t)qt * 4096 + 8);
#pragma unroll
        for (int k = 0; k < 8; k++) { s[k] += (float)v0[k]; s[8 + k] += (float)v1[k]; }
    }
    bf16x8 o0, o1;
#pragma unroll
    for (int k = 0; k < 8; k++) { o0[k] = (bf16)s[k]; o1[k] = (bf16)s[8 + k]; }
    bf16* dst = dG8 + (size_t)(b * N_C + c) * 4096 + threadIdx.x * 16;
    *(bf16x8*)dst = o0;
    *(bf16x8*)(dst + 8) = o1;
}

// ---------------------------------------------------------------------------
// K2b (NEW): exclusive chunk-prefix Gpre[b,c] = sum_{t<c} dG8[b,t].
// Done ONCE here instead of twice (per half) inside K3; removes the serial
// L2-latency scan chain from K3's critical path. Grid (D_B, N_C): x=b so the
// per-b dG8 (256 KB) stays XCD-local and L2-hot from k_fold.
// ---------------------------------------------------------------------------
__global__ __launch_bounds__(256, 4) void k_scan(const bf16* __restrict__ dG8,
                                                 bf16* __restrict__ Gpre)
{
    const int b = blockIdx.x, c = blockIdx.y;
    const bf16* base = dG8 + (size_t)b * N_C * 4096 + threadIdx.x * 16;
    float run[16];
#pragma unroll
    for (int k = 0; k < 16; k++) run[k] = 0.f;
    int t = 0;
    for (; t + 4 <= c; t += 4) {
        bf16x8 v[4][2];
#pragma unroll
        for (int j = 0; j < 4; j++) {
            v[j][0] = *(const bf16x8*)(base + (size_t)(t + j) * 4096);
            v[j][1] = *(const bf16x8*)(base + (size_t)(t + j) * 4096 + 8);
        }
#pragma unroll
        for (int j = 0; j < 4; j++)
#pragma unroll
            for (int k = 0; k < 8; k++) {
                run[k] += (float)v[j][0][k];
                run[8 + k] += (float)v[j][1][k];
            }
    }
    for (; t < c; t++) {
        const bf16x8 v0 = *(const bf16x8*)(base + (size_t)t * 4096);
        const bf16x8 v1 = *(const bf16x8*)(base + (size_t)t * 4096 + 8);
#pragma unroll
        for (int k = 0; k < 8; k++) { run[k] += (float)v0[k]; run[8 + k] += (float)v1[k]; }
    }
    bf16x8 o0, o1;
#pragma unroll
    for (int k = 0; k < 8; k++) { o0[k] = (bf16)run[k]; o1[k] = (bf16)run[8 + k]; }
    bf16* dst = Gpre + (size_t)(b * N_C + c) * 4096 + threadIdx.x * 16;
    *(bf16x8*)dst = o0;
    *(bf16x8*)(dst + 8) = o1;
}

// ---------------------------------------------------------------------------
// One head of the K3 loop, fully static (NU = 2 or 4). Writes S to the given
// slab, reads it back (same-wave in-order DS), accumulates S*Er. (unchanged)
// ---------------------------------------------------------------------------
template <int NU>
static __device__ __forceinline__ void head_iter(
    const bf16* __restrict__ Qh, const bf16* __restrict__ Eh,
    bf16* __restrict__ Sw, const bf16x8 ra0, const bf16x8 ra1,
    int l16, int q, int tbase, f32x4 (&acc)[4])
{
#pragma unroll
    for (int nu = 0; nu < NU; nu++) {
        const bf16x8 b0 = *(const bf16x8*)&Qh[(nu * 16 + l16) * 64 + q * 8];
        const bf16x8 b1 = *(const bf16x8*)&Qh[(nu * 16 + l16) * 64 + 32 + q * 8];
        f32x4 z = {0.f, 0.f, 0.f, 0.f};
        f32x4 sv = mfma16(ra0, b0, z);
        sv = mfma16(ra1, b1, sv);
        const int u_loc = nu * 16 + l16;
#pragma unroll
        for (int r = 0; r < 4; r++) {
            const int t_loc = tbase + q * 4 + r;
            Sw[(q * 4 + r) * NP + u_loc] = (u_loc <= t_loc) ? (bf16)sv[r] : (bf16)0.f;
        }
    }
    const bf16x8 sa0 = *(const bf16x8*)&Sw[l16 * NP + q * 8];
#pragma unroll
    for (int ns = 0; ns < 4; ns++) {
        const bf16x8 e0 = *(const bf16x8*)&Eh[(ns * 16 + l16) * 64 + q * 8];
        acc[ns] = mfma16(sa0, e0, acc[ns]);
    }
    if (NU == 4) {
        const bf16x8 sa1 = *(const bf16x8*)&Sw[l16 * NP + 32 + q * 8];
#pragma unroll
        for (int ns = 0; ns < 4; ns++) {
            const bf16x8 e1 = *(const bf16x8*)&Eh[(ns * 16 + l16) * 64 + 32 + q * 8];
            acc[ns] = mfma16(sa1, e1, acc[ns]);
        }
    }
}

// ---------------------------------------------------------------------------
// K3 (REWRITTEN): quarter-split for occupancy. Block (b, c, qq) computes out
// rows [c*64 + qq*16, +16). Each of the 4 waves owns 2 heads (g*2, g*2+1),
// ping-pong S slabs. No prefix scan here: Gpre tile loaded straight into Gb.
// Prefix-MFMA applied by wave 1 (off the tail). 2-stage Ob reduction keeps
// LDS at 36 KB -> 4 blocks/CU = 16 waves/CU (was 8).
// Grid (D_B, N_C, 4): linear%8 = b (XCD-local); all 4 qq of (b,c) co-resident
// on the same XCD for Qrd/Erd/Gpre L2 reuse.
// ---------------------------------------------------------------------------
__global__ __launch_bounds__(256, 4) void k_out(
    const bf16* __restrict__ Gpre, const bf16* __restrict__ Rbf,
    const bf16* __restrict__ Qrd, const bf16* __restrict__ Erd,
    float* __restrict__ out)
{
    __shared__ bf16 Gb[64 * NP];          // Gcum [i][i']
    __shared__ bf16 Sl[4 * 2 * 16 * NP];  // per-wave ping-pong S slabs
    __shared__ float Ob[2][16 * 65];      // 2-stage cross-wave reduction
    const int b = blockIdx.x, c = blockIdx.y, qq = blockIdx.z;
    const int tid = threadIdx.x;
    const int g = tid >> 6, l = tid & 63, q = l >> 4, l16 = l & 15;

    // Gpre tile -> Gb (replaces the register scan)
    {
        const int row = tid >> 2, col = (tid & 3) * 16;
        const bf16* src = Gpre + (size_t)(b * N_C + c) * 4096 + row * 64 + col;
        *(bf16x8*)&Gb[row * NP + col]     = *(const bf16x8*)src;
        *(bf16x8*)&Gb[row * NP + col + 8] = *(const bf16x8*)(src + 8);
    }

    // A-frags: R rows t = c*64 + qq*16 + l16 (same rows for all 4 waves)
    const int trow = c * 64 + qq * 16 + l16;
    const bf16x8 ra0 = *(const bf16x8*)&Rbf[((size_t)b * N_T + trow) * NN + q * 8];
    const bf16x8 ra1 = *(const bf16x8*)&Rbf[((size_t)b * N_T + trow) * NN + 32 + q * 8];
    __syncthreads();   // Gb visible before wave 1's prefix-MFMA

    // ---- head loop: 2 heads per wave, barrier-free, ping-pong slabs
    bf16* Sw0 = Sl + (g * 2 + 0) * 16 * NP;
    bf16* Sw1 = Sl + (g * 2 + 1) * 16 * NP;
    const int tbase = qq * 16;
    const size_t hb = (((size_t)(b * N_C + c)) * N_H + g * 2) * 4096;
    const bf16* Qg = Qrd + hb;   // this wave's 2 heads, 4096 apart
    const bf16* Eg = Erd + hb;
    f32x4 acc[4];
#pragma unroll
    for (int ns = 0; ns < 4; ns++) { f32x4 z = {0.f, 0.f, 0.f, 0.f}; acc[ns] = z; }

    if (qq >= 2) {
        head_iter<4>(Qg,        Eg,        Sw0, ra0, ra1, l16, q, tbase, acc);
        head_iter<4>(Qg + 4096, Eg + 4096, Sw1, ra0, ra1, l16, q, tbase, acc);
    } else {
        head_iter<2>(Qg,        Eg,        Sw0, ra0, ra1, l16, q, tbase, acc);
        head_iter<2>(Qg + 4096, Eg + 4096, Sw1, ra0, ra1, l16, q, tbase, acc);
    }

    // ---- prefix term on wave 1 (head-independent): acc += R_t * Gcum
    if (g == 1) {
#pragma unroll
        for (int ns = 0; ns < 4; ns++) {
            const bf16x8 g0 = *(const bf16x8*)&Gb[(ns * 16 + l16) * NP + q * 8];
            const bf16x8 g1 = *(const bf16x8*)&Gb[(ns * 16 + l16) * NP + 32 + q * 8];
            acc[ns] = mfma16(ra0, g0, acc[ns]);
            acc[ns] = mfma16(ra1, g1, acc[ns]);
        }
    }

    // ---- 2-stage reduction across the 4 waves (2 barriers, 8.3 KB LDS)
    if (g & 1) {  // waves 1,3 publish
#pragma unroll
        for (int ns = 0; ns < 4; ns++)
#pragma unroll
            for (int r = 0; r < 4; r++)
                Ob[g >> 1][(q * 4 + r) * 65 + ns * 16 + l16] = acc[ns][r];
    }
    __syncthreads();
    if (g == 0) {
#pragma unroll
        for (int ns = 0; ns < 4; ns++)
#pragma unroll
            for (int r = 0; r < 4; r++)
                acc[ns][r] += Ob[0][(q * 4 + r) * 65 + ns * 16 + l16];
    } else if (g == 2) {
#pragma unroll
        for (int ns = 0; ns < 4; ns++)
#pragma unroll
            for (int r = 0; r < 4; r++) {
                acc[ns][r] += Ob[1][(q * 4 + r) * 65 + ns * 16 + l16];
                Ob[1][(q * 4 + r) * 65 + ns * 16 + l16] = acc[ns][r];  // same-thread RAW, safe
            }
    }
    __syncthreads();
    if (g == 0) {
        const int t0 = c * 64 + qq * 16;
#pragma unroll
        for (int ns = 0; ns < 4; ns++)
#pragma unroll
            for (int r = 0; r < 4; r++) {
                const float sum = acc[ns][r] + Ob[1][(q * 4 + r) * 65 + ns * 16 + l16];
                out[((size_t)b * N_T + t0 + q * 4 + r) * NN + ns * 16 + l16] = sum;
            }
    }
}

// ---------------------------------------------------------------------------
extern "C" void kernel_launch(void* const* d_in, const int* in_sizes, int n_in,
                              void* d_out, int out_size, void* d_ws, size_t ws_size,
                              hipStream_t stream) {
    const float* rp = (const float*)d_in[0];   // (8, 2048, 64) fp32
    const float* Qm = (const float*)d_in[1];   // (8, 64, 64)
    const float* Em = (const float*)d_in[2];   // (8, 64, 64)
    float* out = (float*)d_out;                // (8, 2048, 64) fp32

    // ws: dGq 8.4 MB + Rbf 2 MB + Qrd 16.8 MB + Erd 16.8 MB + dG8 2.1 MB + Gpre 2.1 MB
    bf16* dGq = (bf16*)d_ws;
    bf16* Rbf = dGq + (size_t)D_B * N_C * 4 * 4096;
    bf16* Qrd = Rbf + (size_t)D_B * N_T * NN;
    bf16* Erd = Qrd + (size_t)D_B * N_C * N_H * 4096;
    bf16* dG8 = Erd + (size_t)D_B * N_C * N_H * 4096;
    bf16* Gpre = dG8 + (size_t)D_B * N_C * 4096;

    k_dg<<<dim3(D_B, N_C, 4), 256, 0, stream>>>(rp, Qm, Em, dGq, Rbf, Qrd, Erd);
    k_fold<<<dim3(D_B, N_C), 256, 0, stream>>>(dGq, dG8);
    k_scan<<<dim3(D_B, N_C), 256, 0, stream>>>(dG8, Gpre);
    k_out<<<dim3(D_B, N_C, 4), 256, 0, stream>>>(Gpre, Rbf, Qrd, Erd, out);
}

// Round 3
// 101.921 us; speedup vs baseline: 1.0303x; 1.0303x over previous
//
#include <hip/hip_runtime.h>

// Problem constants
#define D_B 8
#define N_T 2048
#define NN  64
#define N_H 8
#define N_C 32   // u-chunks of 64
#define NP  72   // padded LDS row stride (bf16): 144 B rows, 16B-aligned, 2-way alias (free)

typedef __bf16 bf16;
typedef bf16 bf16x8 __attribute__((ext_vector_type(8)));
typedef bf16 bf16x4 __attribute__((ext_vector_type(4)));
typedef float f32x4 __attribute__((ext_vector_type(4)));

static __device__ __forceinline__ f32x4 mfma16(bf16x8 a, bf16x8 b, f32x4 c) {
    // a_frag[j] = A[lane&15][(lane>>4)*8+j]; b_frag[j] = B[(lane>>4)*8+j][lane&15]
    // d[r] = D[(lane>>4)*4+r][lane&15]
    return __builtin_amdgcn_mfma_f32_16x16x32_bf16(a, b, c, 0, 0, 0);
}

static __device__ __forceinline__ bf16x8 ldcvt8(const float* p) {
    const f32x4 v0 = *(const f32x4*)p;
    const f32x4 v1 = *(const f32x4*)(p + 4);
    bf16x8 r;
#pragma unroll
    for (int k = 0; k < 4; k++) { r[k] = (bf16)v0[k]; r[4 + k] = (bf16)v1[k]; }
    return r;
}

// ---------------------------------------------------------------------------
// K1': block (b, c, zz) handles heads {2zz, 2zz+1}. K1 body + DIAGONAL chunk
// fused (S = masked r.Qr^T, acc += S.Er) using the in-LDS Qr/Er tiles — the
// Qrd/Erd/Rbf global round-trips (~74 MB) of the R0/R1 pipeline are gone.
// Outputs: dGq (bf16, pre-transposed [i][i']) and diagq (fp32 diag partials).
// 36.9 KB LDS -> 4 blocks/CU. Grid (D_B, N_C, 4): linear%8 = b (XCD-local).
// Barriers per head: A (Q/E staged) -> B (QT/ET ready) -> C (QT2 ready) ->
// D (diag done). All MFMA fragment maps identical to the R0-proven K1/K3.
// ---------------------------------------------------------------------------
__global__ __launch_bounds__(256, 4) void k_dg(
    const float* __restrict__ rp, const float* __restrict__ Qm,
    const float* __restrict__ Em,
    bf16* __restrict__ dGq, float* __restrict__ diagq)
{
    __shared__ __align__(16) char smem[4 * 64 * NP * 2];  // 36864 B
    bf16* Ql = (bf16*)smem;        // Q_h [i'][j]; later Qr [u][i'] (QT2)
    bf16* El = Ql + 64 * NP;       // E_h [i][j]; later per-wave S slabs
    bf16* QT = El + 64 * NP;       // Qr [i'][u]; dG [i][i'] staging at tail
    bf16* ET = QT + 64 * NP;       // Er [i][u]
    float* fst = (float*)smem;     // fp32 diag staging 64x66 (overlaps Ql+El)

    const int b = blockIdx.x, c = blockIdx.y, zz = blockIdx.z;
    const int tid = threadIdx.x;
    const int w = tid >> 6, l = tid & 63, q = l >> 4, l16 = l & 15;
    const int row = tid >> 2, col = (tid & 3) * 16;

    // A-frags: r' rows u = t = c*64 + w*16 + l16 (shared by Qr/Er/S paths)
    const float* rrow = rp + ((size_t)b * N_T + c * 64 + w * 16 + l16) * NN;
    const bf16x8 a0 = ldcvt8(rrow + q * 8);
    const bf16x8 a1 = ldcvt8(rrow + 32 + q * 8);

    f32x4 dacc[4], acc[4];
#pragma unroll
    for (int ns = 0; ns < 4; ns++) {
        f32x4 z = {0.f, 0.f, 0.f, 0.f};
        dacc[ns] = z; acc[ns] = z;
    }

    for (int hh = 0; hh < 2; hh++) {
        const int h = zz * 2 + hh;
        {
            const float* qs = Qm + (size_t)h * 4096 + row * 64 + col;
            const float* es = Em + (size_t)h * 4096 + row * 64 + col;
            *(bf16x8*)&Ql[row * NP + col]     = ldcvt8(qs);
            *(bf16x8*)&Ql[row * NP + col + 8] = ldcvt8(qs + 8);
            *(bf16x8*)&El[row * NP + col]     = ldcvt8(es);
            *(bf16x8*)&El[row * NP + col + 8] = ldcvt8(es + 8);
        }
        __syncthreads();  // A: Ql/El ready
        // Qr, Er for this wave's 16 u-rows; keep Qr bf16 in regs (pq)
        bf16x4 pq[4];
#pragma unroll
        for (int ns = 0; ns < 4; ns++) {
            bf16x8 b0 = *(const bf16x8*)&Ql[(ns * 16 + l16) * NP + q * 8];
            bf16x8 b1 = *(const bf16x8*)&Ql[(ns * 16 + l16) * NP + 32 + q * 8];
            f32x4 z = {0.f, 0.f, 0.f, 0.f};
            f32x4 s = mfma16(a0, b0, z);
            s = mfma16(a1, b1, s);
            bf16x4 p;
#pragma unroll
            for (int r = 0; r < 4; r++) p[r] = (bf16)s[r];
            pq[ns] = p;
            *(bf16x4*)&QT[(ns * 16 + l16) * NP + w * 16 + q * 4] = p;  // [i'][u]
            b0 = *(const bf16x8*)&El[(ns * 16 + l16) * NP + q * 8];
            b1 = *(const bf16x8*)&El[(ns * 16 + l16) * NP + 32 + q * 8];
            f32x4 s2 = mfma16(a0, b0, z);
            s2 = mfma16(a1, b1, s2);
#pragma unroll
            for (int r = 0; r < 4; r++) p[r] = (bf16)s2[r];
            *(bf16x4*)&ET[(ns * 16 + l16) * NP + w * 16 + q * 4] = p;  // [i][u]
        }
        __syncthreads();  // B: QT/ET ready; Ql/El now dead
        // dG += Qr^T.Er (reads QT/ET); in parallel write QT2 [u][i'] -> Ql
        {
            const bf16x8 qa0 = *(const bf16x8*)&QT[(w * 16 + l16) * NP + q * 8];
            const bf16x8 qa1 = *(const bf16x8*)&QT[(w * 16 + l16) * NP + 32 + q * 8];
#pragma unroll
            for (int ns = 0; ns < 4; ns++) {
                const bf16x8 e0 = *(const bf16x8*)&ET[(ns * 16 + l16) * NP + q * 8];
                const bf16x8 e1 = *(const bf16x8*)&ET[(ns * 16 + l16) * NP + 32 + q * 8];
                dacc[ns] = mfma16(qa0, e0, dacc[ns]);
                dacc[ns] = mfma16(qa1, e1, dacc[ns]);
            }
        }
#pragma unroll
        for (int ns = 0; ns < 4; ns++)
#pragma unroll
            for (int r = 0; r < 4; r++)
                Ql[(w * 16 + q * 4 + r) * NP + ns * 16 + l16] = pq[ns][r];
        __syncthreads();  // C: QT2 (Ql) ready; El dead -> per-wave S slabs
        // Diagonal: S[t][u] = mask(r_t . Qr_u^T), t in wave's 16 rows.
        // Only u-blocks nu <= w can be nonzero (u <= t).
        {
            bf16* Sw = El + (w * 16) * NP;   // this wave's 16-row slab
#pragma unroll
            for (int nu = 0; nu < 4; nu++) {
                if (nu <= w) {
                    const bf16x8 b0 = *(const bf16x8*)&Ql[(nu * 16 + l16) * NP + q * 8];
                    const bf16x8 b1 = *(const bf16x8*)&Ql[(nu * 16 + l16) * NP + 32 + q * 8];
                    f32x4 z = {0.f, 0.f, 0.f, 0.f};
                    f32x4 sv = mfma16(a0, b0, z);
                    sv = mfma16(a1, b1, sv);
                    const int u_loc = nu * 16 + l16;
#pragma unroll
                    for (int r = 0; r < 4; r++) {
                        const int t_loc = w * 16 + q * 4 + r;
                        Sw[(q * 4 + r) * NP + u_loc] = (u_loc <= t_loc) ? (bf16)sv[r] : (bf16)0.f;
                    }
                } else {
#pragma unroll
                    for (int r = 0; r < 4; r++)
                        Sw[(q * 4 + r) * NP + nu * 16 + l16] = (bf16)0.f;
                }
            }
            // same-wave in-order DS read-back; PV: acc += S.Er
            const bf16x8 sa0 = *(const bf16x8*)&Sw[l16 * NP + q * 8];
#pragma unroll
            for (int ns = 0; ns < 4; ns++) {
                const bf16x8 e0 = *(const bf16x8*)&ET[(ns * 16 + l16) * NP + q * 8];
                acc[ns] = mfma16(sa0, e0, acc[ns]);
            }
            if (w >= 2) {
                const bf16x8 sa1 = *(const bf16x8*)&Sw[l16 * NP + 32 + q * 8];
#pragma unroll
                for (int ns = 0; ns < 4; ns++) {
                    const bf16x8 e1 = *(const bf16x8*)&ET[(ns * 16 + l16) * NP + 32 + q * 8];
                    acc[ns] = mfma16(sa1, e1, acc[ns]);
                }
            }
        }
        __syncthreads();  // D: end of head (Ql/El/QT/ET reused next iter)
    }
    // tail: stage dG (bf16, [i][i'] -> QT) and diag (fp32 -> fst)
#pragma unroll
    for (int ns = 0; ns < 4; ns++) {
        bf16x4 p;
#pragma unroll
        for (int r = 0; r < 4; r++) p[r] = (bf16)dacc[ns][r];
        *(bf16x4*)&QT[(ns * 16 + l16) * NP + w * 16 + q * 4] = p;
    }
#pragma unroll
    for (int ns = 0; ns < 4; ns++)
#pragma unroll
        for (int r = 0; r < 4; r++)
            fst[(w * 16 + q * 4 + r) * 66 + ns * 16 + l16] = acc[ns][r];
    __syncthreads();
    {
        bf16* dst = dGq + (((size_t)(b * N_C + c)) * 4 + zz) * 4096 + row * 64 + col;
        *(bf16x8*)dst       = *(const bf16x8*)&QT[row * NP + col];
        *(bf16x8*)(dst + 8) = *(const bf16x8*)&QT[row * NP + col + 8];
        float* dd = diagq + (((size_t)(b * N_C + c)) * 4 + zz) * 4096 + row * 64 + col;
#pragma unroll
        for (int k = 0; k < 4; k++)
            *(f32x4*)(dd + k * 4) = *(const f32x4*)&fst[row * 66 + col + k * 4];
    }
}

// ---------------------------------------------------------------------------
// K2: fold the 4 head-quarters: dG8[b,c] = sum_qt dGq[b,c,qt]. (proven)
// ---------------------------------------------------------------------------
__global__ __launch_bounds__(256, 4) void k_fold(const bf16* __restrict__ dGq,
                                                 bf16* __restrict__ dG8)
{
    const int b = blockIdx.x, c = blockIdx.y;
    const size_t base = ((size_t)(b * N_C + c)) * 4 * 4096 + threadIdx.x * 16;
    float s[16];
#pragma unroll
    for (int k = 0; k < 16; k++) s[k] = 0.f;
#pragma unroll
    for (int qt = 0; qt < 4; qt++) {
        const bf16x8 v0 = *(const bf16x8*)(dGq + base + (size_t)qt * 4096);
        const bf16x8 v1 = *(const bf16x8*)(dGq + base + (size_t)qt * 4096 + 8);
#pragma unroll
        for (int k = 0; k < 8; k++) { s[k] += (float)v0[k]; s[8 + k] += (float)v1[k]; }
    }
    bf16x8 o0, o1;
#pragma unroll
    for (int k = 0; k < 8; k++) { o0[k] = (bf16)s[k]; o1[k] = (bf16)s[8 + k]; }
    bf16* dst = dG8 + (size_t)(b * N_C + c) * 4096 + threadIdx.x * 16;
    *(bf16x8*)dst = o0;
    *(bf16x8*)(dst + 8) = o1;
}

// ---------------------------------------------------------------------------
// K3': block (b, c, zz) -> out rows [c*64 + zz*16, +16). Register scan of
// dG8[b, t<c] (L2-hot, R0-proven) -> Gb; wave w = i-block w: 2 prefix MFMAs;
// fp32 diag fold from diagq; store. 9 KB LDS. Grid (D_B, N_C, 4): %8 = b.
// ---------------------------------------------------------------------------
__global__ __launch_bounds__(256, 4) void k_out(
    const float* __restrict__ rp, const bf16* __restrict__ dG8,
    const float* __restrict__ diagq, float* __restrict__ out)
{
    __shared__ bf16 Gb[64 * NP];   // Gcum [i][i'] bf16
    const int b = blockIdx.x, c = blockIdx.y, zz = blockIdx.z;
    const int tid = threadIdx.x;
    const int w = tid >> 6, l = tid & 63, q = l >> 4, l16 = l & 15;

    // A-frags: r' rows t = c*64 + zz*16 + l16 (direct fp32, L2/L3-resident)
    const float* rr = rp + ((size_t)b * N_T + c * 64 + zz * 16 + l16) * NN;
    const bf16x8 ra0 = ldcvt8(rr + q * 8);
    const bf16x8 ra1 = ldcvt8(rr + 32 + q * 8);

    // diag fold (fp32): wave w owns i-block w
    float dsum[4];
#pragma unroll
    for (int r = 0; r < 4; r++) {
        float sgm = 0.f;
#pragma unroll
        for (int qt = 0; qt < 4; qt++)
            sgm += diagq[(((size_t)(b * N_C + c)) * 4 + qt) * 4096 +
                         (zz * 16 + q * 4 + r) * 64 + w * 16 + l16];
        dsum[r] = sgm;
    }

    // register scan of dG8[b, t<c] (L2-hot), batch-4
    float run[16];
#pragma unroll
    for (int k = 0; k < 16; k++) run[k] = 0.f;
    {
        const bf16* base = dG8 + (size_t)b * N_C * 4096 + tid * 16;
        int t = 0;
        for (; t + 4 <= c; t += 4) {
            bf16x8 v[4][2];
#pragma unroll
            for (int j = 0; j < 4; j++) {
                v[j][0] = *(const bf16x8*)(base + (size_t)(t + j) * 4096);
                v[j][1] = *(const bf16x8*)(base + (size_t)(t + j) * 4096 + 8);
            }
#pragma unroll
            for (int j = 0; j < 4; j++)
#pragma unroll
                for (int k = 0; k < 8; k++) {
                    run[k] += (float)v[j][0][k];
                    run[8 + k] += (float)v[j][1][k];
                }
        }
        for (; t < c; t++) {
            const bf16x8 v0 = *(const bf16x8*)(base + (size_t)t * 4096);
            const bf16x8 v1 = *(const bf16x8*)(base + (size_t)t * 4096 + 8);
#pragma unroll
            for (int k = 0; k < 8; k++) { run[k] += (float)v0[k]; run[8 + k] += (float)v1[k]; }
        }
    }
    {
        bf16x8 o0, o1;
#pragma unroll
        for (int k = 0; k < 8; k++) { o0[k] = (bf16)run[k]; o1[k] = (bf16)run[8 + k]; }
        *(bf16x8*)&Gb[(tid >> 2) * NP + (tid & 3) * 16]     = o0;
        *(bf16x8*)&Gb[(tid >> 2) * NP + (tid & 3) * 16 + 8] = o1;
    }
    __syncthreads();  // Gb ready
    f32x4 pacc = {0.f, 0.f, 0.f, 0.f};
    const bf16x8 g0 = *(const bf16x8*)&Gb[(w * 16 + l16) * NP + q * 8];
    const bf16x8 g1 = *(const bf16x8*)&Gb[(w * 16 + l16) * NP + 32 + q * 8];
    pacc = mfma16(ra0, g0, pacc);
    pacc = mfma16(ra1, g1, pacc);
#pragma unroll
    for (int r = 0; r < 4; r++)
        out[((size_t)b * N_T + c * 64 + zz * 16 + q * 4 + r) * NN + w * 16 + l16] =
            pacc[r] + dsum[r];
}

// ---------------------------------------------------------------------------
extern "C" void kernel_launch(void* const* d_in, const int* in_sizes, int n_in,
                              void* d_out, int out_size, void* d_ws, size_t ws_size,
                              hipStream_t stream) {
    const float* rp = (const float*)d_in[0];   // (8, 2048, 64) fp32
    const float* Qm = (const float*)d_in[1];   // (8, 64, 64)
    const float* Em = (const float*)d_in[2];   // (8, 64, 64)
    float* out = (float*)d_out;                // (8, 2048, 64) fp32

    // ws: dGq 8.4 MB (bf16) + diagq 16.8 MB (fp32) + dG8 2.1 MB (bf16)
    bf16* dGq = (bf16*)d_ws;
    float* diagq = (float*)(dGq + (size_t)D_B * N_C * 4 * 4096);
    bf16* dG8 = (bf16*)(diagq + (size_t)D_B * N_C * 4 * 4096);

    k_dg<<<dim3(D_B, N_C, 4), 256, 0, stream>>>(rp, Qm, Em, dGq, diagq);
    k_fold<<<dim3(D_B, N_C), 256, 0, stream>>>(dGq, dG8);
    k_out<<<dim3(D_B, N_C, 4), 256, 0, stream>>>(rp, dG8, diagq, out);
}